// Round 19
// baseline (1784.928 us; speedup 1.0000x reference)
//
#include <hip/hip_runtime.h>
#include <stdint.h>

// GeneDynamics: out = -x + (A @ x^2) / (x^2 + 1)
// v15: v13 (1 KiB A-bursts, ROWS=32, KC=256) + bf16 X tile:
//      X LDS reads halve (64->32 b128/wave-chunk), tX 16->8 KiB ->
//      40 KiB/block -> 4 blocks/CU. LDS drops below the HBM floor.

#define NN 16384
#define DIM 16
#define TPB 256                // 4 waves
#define ROWS 32                // rows per block
#define NRB 512                // NN / ROWS
#define KSPLIT 2
#define KRANGE 8192            // NN / KSPLIT
#define KC 256                 // k per chunk (1 KiB per row per chunk)
#define NCH 32                 // KRANGE / KC

__device__ __forceinline__ uint32_t f2bf(float f) {   // round-to-nearest-even
    uint32_t u = __float_as_uint(f);
    return (u + 0x7fffu + ((u >> 16) & 1u)) >> 16;
}

// prep: out = -x ; inv = 1/(x^2+1) ; xhb[k] = 8 u32 of packed bf16(x^2) pairs
__global__ __launch_bounds__(256) void prep_kernel(const float* __restrict__ x,
                                                   float* __restrict__ out,
                                                   uint32_t* __restrict__ xhb,
                                                   float* __restrict__ inv) {
    int i = blockIdx.x * 256 + threadIdx.x;            // row 0..16383
    const float4* xr = reinterpret_cast<const float4*>(x + (size_t)i * DIM);
    float4* orow = reinterpret_cast<float4*>(out + (size_t)i * DIM);
    float4* irow = reinterpret_cast<float4*>(inv + (size_t)i * DIM);
    uint32_t* xb = xhb + (size_t)i * 8;
    #pragma unroll
    for (int v = 0; v < 4; ++v) {
        float4 xv = xr[v];
        orow[v] = make_float4(-xv.x, -xv.y, -xv.z, -xv.w);
        float4 h = make_float4(xv.x * xv.x, xv.y * xv.y, xv.z * xv.z, xv.w * xv.w);
        irow[v] = make_float4(1.f / (h.x + 1.f), 1.f / (h.y + 1.f),
                              1.f / (h.z + 1.f), 1.f / (h.w + 1.f));
        xb[2 * v]     = f2bf(h.x) | (f2bf(h.y) << 16);   // d=4v, 4v+1
        xb[2 * v + 1] = f2bf(h.z) | (f2bf(h.w) << 16);   // d=4v+2, 4v+3
    }
}

__device__ __forceinline__ void gload_lds16(const void* g, void* l, int nt) {
    if (nt)
        __builtin_amdgcn_global_load_lds(
            (const __attribute__((address_space(1))) void*)g,
            (__attribute__((address_space(3))) void*)l, 16, 0, 2 /*NT*/);
    else
        __builtin_amdgcn_global_load_lds(
            (const __attribute__((address_space(1))) void*)g,
            (__attribute__((address_space(3))) void*)l, 16, 0, 0);
}

__global__ __launch_bounds__(TPB, 4) void agg_kernel(const float* __restrict__ A,
                                                     const uint32_t* __restrict__ xhb,
                                                     const float* __restrict__ inv,
                                                     float* __restrict__ out) {
    // tA[32 rows][256 k] f32: row r holds logical f4-slot s at phys s^(r&7).
    // tXb: 512 16B-slots of bf16 pairs; logical slot p at phys p^(((p>>4)&3)<<1)
    //   (involution: key bits 4-5 disjoint from XOR bits 1-2). Compute reads
    //   land <=2-way bank-aliased (free, m136).
    __shared__ float    tA[ROWS * KC];   // 32 KiB
    __shared__ uint32_t tXb[KC * 8];     // 8 KiB  (40 KiB -> 4 blocks/CU)

    const int tid = threadIdx.x;
    const int l = tid & 63, w = tid >> 6, m = l & 15, q = l >> 4;
    const int rb = blockIdx.x & (NRB - 1);
    const int ks = blockIdx.x >> 9;
    const int r0 = rb * ROWS;
    const size_t k0 = (size_t)ks * KRANGE;

    // ---- A staging: wave w, instr i (0..7) -> row 8w+i; lane l loads logical
    //      f4-slot l^(i&7) of that row's 1 KiB chunk segment (contiguous) ----
    const float* Ab = A + (size_t)(r0 + 8 * w) * NN + k0;
    int aoff[8];
    #pragma unroll
    for (int i = 0; i < 8; ++i) aoff[i] = 4 * (l ^ (i & 7));

    // ---- X staging: instr J = 2w+j covers phys 16B-slots J*64 + l ----
    const char* Xc = (const char*)(xhb + k0 * 8);
    int xboff[2];
    #pragma unroll
    for (int j = 0; j < 2; ++j) {
        int P = (2 * w + j) * 64 + l;
        int L = P ^ (((P >> 4) & 3) << 1);
        xboff[j] = L * 16;                       // source byte offset in chunk
    }

    // ---- compute-side indices (loop-invariant) ----
    // thread (w,q,m): rows m, m+16; k = 64w+16q+4b+e
    int rA[2][4];
    #pragma unroll
    for (int j = 0; j < 2; ++j)
        #pragma unroll
        for (int b = 0; b < 4; ++b)
            rA[j][b] = (m + 16 * j) * KC + 4 * ((16 * w + 4 * q + b) ^ (m & 7));
    const int base2 = 128 * w + 32 * q;          // logical 16B-slot base (2k0_loc)
    const int K0 = ((2 * q) & 3) << 1;           // swizzle key for c<8
    const int K1 = ((2 * q + 1) & 3) << 1;       // swizzle key for c>=8

    float4 acc[2][4];   // [row j][d-quad v] = 32 floats
    #pragma unroll
    for (int j = 0; j < 2; ++j)
        #pragma unroll
        for (int v = 0; v < 4; ++v) acc[j][v] = make_float4(0.f, 0.f, 0.f, 0.f);

    for (int t = 0; t < NCH; ++t) {
        __syncthreads();                 // tile t-1 fully consumed by all waves
        // ---- STAGE(t): 8 A-instrs (1 KiB contiguous, NT) + 2 X-instrs ----
        {
            const float* sA = Ab + (size_t)t * KC;
            #pragma unroll
            for (int i = 0; i < 8; ++i)
                gload_lds16(sA + (size_t)i * NN + aoff[i], &tA[(8 * w + i) * KC], 1);
            const char* sX = Xc + (size_t)t * (KC * 32);
            #pragma unroll
            for (int j = 0; j < 2; ++j)
                gload_lds16(sX + xboff[j], &tXb[(2 * w + j) * 256], 0);
        }
        __syncthreads();                 // drain: tile t resident
        // ---- COMPUTE(t) ----
        #pragma unroll
        for (int b = 0; b < 4; ++b) {
            float4 ar[2];
            ar[0] = *reinterpret_cast<const float4*>(&tA[rA[0][b]]);
            ar[1] = *reinterpret_cast<const float4*>(&tA[rA[1][b]]);
            #pragma unroll
            for (int e = 0; e < 4; ++e) {
                const int c = 4 * b + e;                     // unroll-const
                const int p0 = base2 + ((2 * c) ^ (c < 8 ? K0 : K1));
                uint4 X0 = *reinterpret_cast<const uint4*>(&tXb[p0 * 4]);
                uint4 X1 = *reinterpret_cast<const uint4*>(&tXb[(p0 + 1) * 4]);
                float xq[16];
                {
                    const uint32_t* u = &X0.x;
                    #pragma unroll
                    for (int jj = 0; jj < 4; ++jj) {
                        xq[2 * jj]     = __uint_as_float(u[jj] << 16);
                        xq[2 * jj + 1] = __uint_as_float(u[jj] & 0xffff0000u);
                    }
                    const uint32_t* u2 = &X1.x;
                    #pragma unroll
                    for (int jj = 0; jj < 4; ++jj) {
                        xq[8 + 2 * jj]     = __uint_as_float(u2[jj] << 16);
                        xq[8 + 2 * jj + 1] = __uint_as_float(u2[jj] & 0xffff0000u);
                    }
                }
                #pragma unroll
                for (int j = 0; j < 2; ++j) {
                    const float a = (&ar[j].x)[e];           // e unroll-const
                    #pragma unroll
                    for (int v = 0; v < 4; ++v) {
                        acc[j][v].x += a * xq[4 * v + 0];
                        acc[j][v].y += a * xq[4 * v + 1];
                        acc[j][v].z += a * xq[4 * v + 2];
                        acc[j][v].w += a * xq[4 * v + 3];
                    }
                }
            }
        }
    }

    // ---- merge the 4 k-phases q (lane bits 4,5) ----
    #pragma unroll
    for (int j = 0; j < 2; ++j)
        #pragma unroll
        for (int v = 0; v < 4; ++v) {
            acc[j][v].x += __shfl_xor(acc[j][v].x, 16);
            acc[j][v].y += __shfl_xor(acc[j][v].y, 16);
            acc[j][v].z += __shfl_xor(acc[j][v].z, 16);
            acc[j][v].w += __shfl_xor(acc[j][v].w, 16);
            acc[j][v].x += __shfl_xor(acc[j][v].x, 32);
            acc[j][v].y += __shfl_xor(acc[j][v].y, 32);
            acc[j][v].z += __shfl_xor(acc[j][v].z, 32);
            acc[j][v].w += __shfl_xor(acc[j][v].w, 32);
        }

    // q==0 lanes write rows m, m+16; waves + KSPLIT merge via atomics
    // (epilogue is linear in agg -> split-K exact)
    if (q == 0) {
        #pragma unroll
        for (int j = 0; j < 2; ++j) {
            const int R = r0 + m + 16 * j;
            const float4* iv4 = reinterpret_cast<const float4*>(inv + (size_t)R * DIM);
            float* orow = out + (size_t)R * DIM;
            #pragma unroll
            for (int v = 0; v < 4; ++v) {
                float4 iv = iv4[v];
                atomicAdd(&orow[4 * v + 0], acc[j][v].x * iv.x);
                atomicAdd(&orow[4 * v + 1], acc[j][v].y * iv.y);
                atomicAdd(&orow[4 * v + 2], acc[j][v].z * iv.z);
                atomicAdd(&orow[4 * v + 3], acc[j][v].w * iv.w);
            }
        }
    }
}

extern "C" void kernel_launch(void* const* d_in, const int* in_sizes, int n_in,
                              void* d_out, int out_size, void* d_ws, size_t ws_size,
                              hipStream_t stream) {
    const float* A = (const float*)d_in[0];
    const float* x = (const float*)d_in[1];
    float* out = (float*)d_out;
    uint32_t* xhb = (uint32_t*)d_ws;                          // 512 KiB
    float* inv = (float*)((char*)d_ws + 512 * 1024);          // 1 MiB

    prep_kernel<<<NN / 256, 256, 0, stream>>>(x, out, xhb, inv);
    agg_kernel<<<NRB * KSPLIT, TPB, 0, stream>>>(A, xhb, inv, out);
}

// Round 20
// 449.817 us; speedup vs baseline: 3.9681x; 3.9681x over previous
//
#include <hip/hip_runtime.h>
#include <stdint.h>

// GeneDynamics: out = -x + (A @ x^2) / (x^2 + 1)
// v16: v15 (bf16 X tile, 1 KiB A-bursts, 40 KiB -> 4 blocks/CU) with the
//      register allocator actually capped: amdgpu_waves_per_eu(1,4) gives a
//      128-VGPR budget (no spill-chasing 8 waves/EU). NO launch_bounds min.

#define NN 16384
#define DIM 16
#define TPB 256                // 4 waves
#define ROWS 32                // rows per block
#define NRB 512                // NN / ROWS
#define KSPLIT 2
#define KRANGE 8192            // NN / KSPLIT
#define KC 256                 // k per chunk (1 KiB per row per chunk)
#define NCH 32                 // KRANGE / KC

__device__ __forceinline__ uint32_t f2bf(float f) {   // round-to-nearest-even
    uint32_t u = __float_as_uint(f);
    return (u + 0x7fffu + ((u >> 16) & 1u)) >> 16;
}

// prep: out = -x ; inv = 1/(x^2+1) ; xhb[k] = 8 u32 of packed bf16(x^2) pairs
__global__ __launch_bounds__(256) void prep_kernel(const float* __restrict__ x,
                                                   float* __restrict__ out,
                                                   uint32_t* __restrict__ xhb,
                                                   float* __restrict__ inv) {
    int i = blockIdx.x * 256 + threadIdx.x;            // row 0..16383
    const float4* xr = reinterpret_cast<const float4*>(x + (size_t)i * DIM);
    float4* orow = reinterpret_cast<float4*>(out + (size_t)i * DIM);
    float4* irow = reinterpret_cast<float4*>(inv + (size_t)i * DIM);
    uint32_t* xb = xhb + (size_t)i * 8;
    #pragma unroll
    for (int v = 0; v < 4; ++v) {
        float4 xv = xr[v];
        orow[v] = make_float4(-xv.x, -xv.y, -xv.z, -xv.w);
        float4 h = make_float4(xv.x * xv.x, xv.y * xv.y, xv.z * xv.z, xv.w * xv.w);
        irow[v] = make_float4(1.f / (h.x + 1.f), 1.f / (h.y + 1.f),
                              1.f / (h.z + 1.f), 1.f / (h.w + 1.f));
        xb[2 * v]     = f2bf(h.x) | (f2bf(h.y) << 16);   // d=4v, 4v+1
        xb[2 * v + 1] = f2bf(h.z) | (f2bf(h.w) << 16);   // d=4v+2, 4v+3
    }
}

__device__ __forceinline__ void gload_lds16(const void* g, void* l, int nt) {
    if (nt)
        __builtin_amdgcn_global_load_lds(
            (const __attribute__((address_space(1))) void*)g,
            (__attribute__((address_space(3))) void*)l, 16, 0, 2 /*NT*/);
    else
        __builtin_amdgcn_global_load_lds(
            (const __attribute__((address_space(1))) void*)g,
            (__attribute__((address_space(3))) void*)l, 16, 0, 0);
}

__global__ __launch_bounds__(TPB)
__attribute__((amdgpu_waves_per_eu(1, 4)))     // VGPR budget 128: spill-proof
void agg_kernel(const float* __restrict__ A,
                const uint32_t* __restrict__ xhb,
                const float* __restrict__ inv,
                float* __restrict__ out) {
    // tA[32 rows][256 k] f32: row r holds logical f4-slot s at phys s^(r&7).
    // tXb: 512 16B-slots of bf16 pairs; logical slot p at phys p^(((p>>4)&3)<<1)
    //   (involution: key bits 4-5 disjoint from XOR bits 1-2).
    __shared__ float    tA[ROWS * KC];   // 32 KiB
    __shared__ uint32_t tXb[KC * 8];     // 8 KiB  (40 KiB -> 4 blocks/CU)

    const int tid = threadIdx.x;
    const int l = tid & 63, w = tid >> 6, m = l & 15, q = l >> 4;
    const int rb = blockIdx.x & (NRB - 1);
    const int ks = blockIdx.x >> 9;
    const int r0 = rb * ROWS;
    const size_t k0 = (size_t)ks * KRANGE;

    // ---- A staging: wave w, instr i (0..7) -> row 8w+i; lane l loads logical
    //      f4-slot l^(i&7) of that row's 1 KiB chunk segment (contiguous) ----
    const float* Ab = A + (size_t)(r0 + 8 * w) * NN + k0;
    int aoff[8];
    #pragma unroll
    for (int i = 0; i < 8; ++i) aoff[i] = 4 * (l ^ (i & 7));

    // ---- X staging: instr J = 2w+j covers phys 16B-slots J*64 + l ----
    const char* Xc = (const char*)(xhb + k0 * 8);
    int xboff[2];
    #pragma unroll
    for (int j = 0; j < 2; ++j) {
        int P = (2 * w + j) * 64 + l;
        int L = P ^ (((P >> 4) & 3) << 1);
        xboff[j] = L * 16;                       // source byte offset in chunk
    }

    // ---- compute-side indices (loop-invariant) ----
    // thread (w,q,m): rows m, m+16; k = 64w+16q+4b+e
    int rA[2][4];
    #pragma unroll
    for (int j = 0; j < 2; ++j)
        #pragma unroll
        for (int b = 0; b < 4; ++b)
            rA[j][b] = (m + 16 * j) * KC + 4 * ((16 * w + 4 * q + b) ^ (m & 7));
    const int base2 = 128 * w + 32 * q;          // logical 16B-slot base
    const int K0 = ((2 * q) & 3) << 1;           // swizzle key, c < 8
    const int K1 = ((2 * q + 1) & 3) << 1;       // swizzle key, c >= 8

    float4 acc[2][4];   // [row j][d-quad v] = 32 floats
    #pragma unroll
    for (int j = 0; j < 2; ++j)
        #pragma unroll
        for (int v = 0; v < 4; ++v) acc[j][v] = make_float4(0.f, 0.f, 0.f, 0.f);

    for (int t = 0; t < NCH; ++t) {
        __syncthreads();                 // tile t-1 fully consumed by all waves
        // ---- STAGE(t): 8 A-instrs (1 KiB contiguous, NT) + 2 X-instrs ----
        {
            const float* sA = Ab + (size_t)t * KC;
            #pragma unroll
            for (int i = 0; i < 8; ++i)
                gload_lds16(sA + (size_t)i * NN + aoff[i], &tA[(8 * w + i) * KC], 1);
            const char* sX = Xc + (size_t)t * (KC * 32);
            #pragma unroll
            for (int j = 0; j < 2; ++j)
                gload_lds16(sX + xboff[j], &tXb[(2 * w + j) * 256], 0);
        }
        __syncthreads();                 // drain: tile t resident
        // ---- COMPUTE(t) ----
        #pragma unroll
        for (int b = 0; b < 4; ++b) {
            float4 ar[2];
            ar[0] = *reinterpret_cast<const float4*>(&tA[rA[0][b]]);
            ar[1] = *reinterpret_cast<const float4*>(&tA[rA[1][b]]);
            #pragma unroll
            for (int e = 0; e < 4; ++e) {
                const int c = 4 * b + e;                     // unroll-const
                const int p0 = base2 + ((2 * c) ^ (c < 8 ? K0 : K1));
                // ---- half 1: d = 0..7 (one uint4, unpack 8, FMA 16) ----
                {
                    uint4 X0 = *reinterpret_cast<const uint4*>(&tXb[p0 * 4]);
                    const uint32_t* u = &X0.x;
                    float xq[8];
                    #pragma unroll
                    for (int jj = 0; jj < 4; ++jj) {
                        xq[2 * jj]     = __uint_as_float(u[jj] << 16);
                        xq[2 * jj + 1] = __uint_as_float(u[jj] & 0xffff0000u);
                    }
                    #pragma unroll
                    for (int j = 0; j < 2; ++j) {
                        const float a = (&ar[j].x)[e];
                        #pragma unroll
                        for (int v = 0; v < 2; ++v) {
                            acc[j][v].x += a * xq[4 * v + 0];
                            acc[j][v].y += a * xq[4 * v + 1];
                            acc[j][v].z += a * xq[4 * v + 2];
                            acc[j][v].w += a * xq[4 * v + 3];
                        }
                    }
                }
                // ---- half 2: d = 8..15 ----
                {
                    uint4 X1 = *reinterpret_cast<const uint4*>(&tXb[(p0 + 1) * 4]);
                    const uint32_t* u = &X1.x;
                    float xq[8];
                    #pragma unroll
                    for (int jj = 0; jj < 4; ++jj) {
                        xq[2 * jj]     = __uint_as_float(u[jj] << 16);
                        xq[2 * jj + 1] = __uint_as_float(u[jj] & 0xffff0000u);
                    }
                    #pragma unroll
                    for (int j = 0; j < 2; ++j) {
                        const float a = (&ar[j].x)[e];
                        #pragma unroll
                        for (int v = 0; v < 2; ++v) {
                            acc[j][v + 2].x += a * xq[4 * v + 0];
                            acc[j][v + 2].y += a * xq[4 * v + 1];
                            acc[j][v + 2].z += a * xq[4 * v + 2];
                            acc[j][v + 2].w += a * xq[4 * v + 3];
                        }
                    }
                }
            }
        }
    }

    // ---- merge the 4 k-phases q (lane bits 4,5) ----
    #pragma unroll
    for (int j = 0; j < 2; ++j)
        #pragma unroll
        for (int v = 0; v < 4; ++v) {
            acc[j][v].x += __shfl_xor(acc[j][v].x, 16);
            acc[j][v].y += __shfl_xor(acc[j][v].y, 16);
            acc[j][v].z += __shfl_xor(acc[j][v].z, 16);
            acc[j][v].w += __shfl_xor(acc[j][v].w, 16);
            acc[j][v].x += __shfl_xor(acc[j][v].x, 32);
            acc[j][v].y += __shfl_xor(acc[j][v].y, 32);
            acc[j][v].z += __shfl_xor(acc[j][v].z, 32);
            acc[j][v].w += __shfl_xor(acc[j][v].w, 32);
        }

    // q==0 lanes write rows m, m+16; waves + KSPLIT merge via atomics
    // (epilogue is linear in agg -> split-K exact)
    if (q == 0) {
        #pragma unroll
        for (int j = 0; j < 2; ++j) {
            const int R = r0 + m + 16 * j;
            const float4* iv4 = reinterpret_cast<const float4*>(inv + (size_t)R * DIM);
            float* orow = out + (size_t)R * DIM;
            #pragma unroll
            for (int v = 0; v < 4; ++v) {
                float4 iv = iv4[v];
                atomicAdd(&orow[4 * v + 0], acc[j][v].x * iv.x);
                atomicAdd(&orow[4 * v + 1], acc[j][v].y * iv.y);
                atomicAdd(&orow[4 * v + 2], acc[j][v].z * iv.z);
                atomicAdd(&orow[4 * v + 3], acc[j][v].w * iv.w);
            }
        }
    }
}

extern "C" void kernel_launch(void* const* d_in, const int* in_sizes, int n_in,
                              void* d_out, int out_size, void* d_ws, size_t ws_size,
                              hipStream_t stream) {
    const float* A = (const float*)d_in[0];
    const float* x = (const float*)d_in[1];
    float* out = (float*)d_out;
    uint32_t* xhb = (uint32_t*)d_ws;                          // 512 KiB
    float* inv = (float*)((char*)d_ws + 512 * 1024);          // 1 MiB

    prep_kernel<<<NN / 256, 256, 0, stream>>>(x, out, xhb, inv);
    agg_kernel<<<NRB * KSPLIT, TPB, 0, stream>>>(A, xhb, inv, out);
}

// Round 21
// 240.193 us; speedup vs baseline: 7.4312x; 1.8727x over previous
//
#include <hip/hip_runtime.h>
#include <stdint.h>

// GeneDynamics: out = -x + (A @ x^2) / (x^2 + 1)
// v17: v13 base (1 KiB A-bursts, ROWS=32, KC=256, 48 KiB -> 3 blocks/CU, NT)
//      with 4-rows-per-thread compute partition (m8 x q8): LDS reads per
//      wave-chunk 72 -> 40 (102 us total, below the 171 us HBM floor).
//      Full 4-instr linear X staging. waves_per_eu(1,3) spill-guard.

#define NN 16384
#define DIM 16
#define TPB 256                // 4 waves
#define ROWS 32                // rows per block
#define NRB 512                // NN / ROWS
#define KSPLIT 2
#define KRANGE 8192            // NN / KSPLIT
#define KC 256                 // k per chunk (1 KiB per row per chunk)
#define NCH 32                 // KRANGE / KC

// prep: out = -x ; xh = x^2 ; inv = 1/(x^2+1)
__global__ __launch_bounds__(256) void prep_kernel(const float* __restrict__ x,
                                                   float* __restrict__ out,
                                                   float* __restrict__ xh,
                                                   float* __restrict__ inv) {
    int i = blockIdx.x * 256 + threadIdx.x;            // 65536 float4s
    float4 v = reinterpret_cast<const float4*>(x)[i];
    reinterpret_cast<float4*>(out)[i] = make_float4(-v.x, -v.y, -v.z, -v.w);
    float4 h = make_float4(v.x * v.x, v.y * v.y, v.z * v.z, v.w * v.w);
    reinterpret_cast<float4*>(xh)[i] = h;
    reinterpret_cast<float4*>(inv)[i] =
        make_float4(1.0f / (h.x + 1.0f), 1.0f / (h.y + 1.0f),
                    1.0f / (h.z + 1.0f), 1.0f / (h.w + 1.0f));
}

__device__ __forceinline__ void gload_lds16(const void* g, void* l, int nt) {
    if (nt)
        __builtin_amdgcn_global_load_lds(
            (const __attribute__((address_space(1))) void*)g,
            (__attribute__((address_space(3))) void*)l, 16, 0, 2 /*NT*/);
    else
        __builtin_amdgcn_global_load_lds(
            (const __attribute__((address_space(1))) void*)g,
            (__attribute__((address_space(3))) void*)l, 16, 0, 0);
}

__device__ __forceinline__ float4 shfl_xor4(float4 v, int mask) {
    return make_float4(__shfl_xor(v.x, mask), __shfl_xor(v.y, mask),
                       __shfl_xor(v.z, mask), __shfl_xor(v.w, mask));
}

__global__ __launch_bounds__(TPB)
__attribute__((amdgpu_waves_per_eu(1, 3)))     // ~170 VGPR budget: spill-proof
void agg_kernel(const float* __restrict__ A,
                const float* __restrict__ xh,
                const float* __restrict__ inv,
                float* __restrict__ out) {
    // tA[32 rows][256 k]: row r holds logical f4-slot s at phys s^(r&7)
    //   (involution carried on the per-lane SOURCE address; dest lane-linear).
    // tX[256 k][16 d]: PLAIN layout (X reads have <=2 addrs per 16-lane phase
    //   -> conflict-free without swizzle).
    __shared__ float tA[ROWS * KC];   // 32 KiB
    __shared__ float tX[KC * DIM];    // 16 KiB   (48 KiB -> 3 blocks/CU)

    const int tid = threadIdx.x;
    const int l = tid & 63, w = tid >> 6;
    const int m8 = l & 7, q8 = l >> 3;        // 4 rows/thread, 8 k-phases
    const int rb = blockIdx.x & (NRB - 1);
    const int ks = blockIdx.x >> 9;
    const int r0 = rb * ROWS;
    const size_t k0 = (size_t)ks * KRANGE;

    // ---- A staging: wave w, instr i (0..7) -> row 8w+i; lane l loads logical
    //      f4-slot l^(i&7) of that row's 1 KiB chunk segment ----
    const float* Ab = A + (size_t)(r0 + 8 * w) * NN + k0;
    int aoff[8];
    #pragma unroll
    for (int i = 0; i < 8; ++i) aoff[i] = 4 * (l ^ (i & 7));

    // ---- X staging: FULL coverage, plain linear: instr j (0..3) covers
    //      floats [(4w+j)*256, +256) ----
    const float* Xc = xh + k0 * DIM;
    int xoff[4];
    #pragma unroll
    for (int j = 0; j < 4; ++j) xoff[j] = (4 * w + j) * 256 + 4 * l;

    // ---- compute-side indices (loop-invariant) ----
    // thread (w,q8,m8): rows m8+8j (j=0..3), k = 64w + 8q8 + 4b + e
    int rA[4][2];
    #pragma unroll
    for (int j = 0; j < 4; ++j)
        #pragma unroll
        for (int b = 0; b < 2; ++b)
            rA[j][b] = (m8 + 8 * j) * KC + 4 * ((16 * w + 2 * q8 + b) ^ m8);
    const int XBASE = (64 * w + 8 * q8) * 16;

    float4 acc[4][4];   // [row j][d-quad v] = 64 floats
    #pragma unroll
    for (int j = 0; j < 4; ++j)
        #pragma unroll
        for (int v = 0; v < 4; ++v) acc[j][v] = make_float4(0.f, 0.f, 0.f, 0.f);

    for (int t = 0; t < NCH; ++t) {
        __syncthreads();                 // tile t-1 fully consumed by all waves
        // ---- STAGE(t): 8 A-instrs (1 KiB contiguous, NT) + 4 X-instrs ----
        {
            const float* sA = Ab + (size_t)t * KC;
            #pragma unroll
            for (int i = 0; i < 8; ++i)
                gload_lds16(sA + (size_t)i * NN + aoff[i], &tA[(8 * w + i) * KC], 1);
            const float* sX = Xc + (size_t)t * (KC * DIM);
            #pragma unroll
            for (int j = 0; j < 4; ++j)
                gload_lds16(sX + xoff[j], &tX[(4 * w + j) * 256], 0);
        }
        __syncthreads();                 // drain: tile t resident
        // ---- COMPUTE(t): 8 A + 32 X ds_read_b128 + 512 FMA per thread ----
        #pragma unroll
        for (int b = 0; b < 2; ++b) {
            float4 ar[4];
            #pragma unroll
            for (int j = 0; j < 4; ++j)
                ar[j] = *reinterpret_cast<const float4*>(&tA[rA[j][b]]);
            #pragma unroll
            for (int e = 0; e < 4; ++e) {
                const int xb = XBASE + (4 * b + e) * 16;   // k-row base in tX
                float4 xv[4];
                #pragma unroll
                for (int v = 0; v < 4; ++v)
                    xv[v] = *reinterpret_cast<const float4*>(&tX[xb + 4 * v]);
                #pragma unroll
                for (int j = 0; j < 4; ++j) {
                    const float a = (&ar[j].x)[e];         // e unroll-const
                    #pragma unroll
                    for (int v = 0; v < 4; ++v) {
                        acc[j][v].x += a * xv[v].x;
                        acc[j][v].y += a * xv[v].y;
                        acc[j][v].z += a * xv[v].z;
                        acc[j][v].w += a * xv[v].w;
                    }
                }
            }
        }
    }

    // ---- 3-stage half-exchange butterfly over the 8 k-phases q8 ----
    // flat idx f = j*16 + d; final: lane holds f in [8*q8, 8*q8+8)
    {
        const int b2 = (q8 >> 2) & 1, b1 = (q8 >> 1) & 1, b0 = q8 & 1;
        // stage mask 32: split f bit5 (j>=2)
        #pragma unroll
        for (int j = 0; j < 2; ++j)
            #pragma unroll
            for (int v = 0; v < 4; ++v) {
                float4 send = b2 ? acc[j][v] : acc[j + 2][v];
                float4 keep = b2 ? acc[j + 2][v] : acc[j][v];
                float4 r = shfl_xor4(send, 32);
                acc[j][v] = make_float4(keep.x + r.x, keep.y + r.y,
                                        keep.z + r.z, keep.w + r.w);
            }
        // stage mask 16: split f bit4 (j parity)
        #pragma unroll
        for (int v = 0; v < 4; ++v) {
            float4 send = b1 ? acc[0][v] : acc[1][v];
            float4 keep = b1 ? acc[1][v] : acc[0][v];
            float4 r = shfl_xor4(send, 16);
            acc[0][v] = make_float4(keep.x + r.x, keep.y + r.y,
                                    keep.z + r.z, keep.w + r.w);
        }
        // stage mask 8: split f bit3 (d >= 8)
        #pragma unroll
        for (int v = 0; v < 2; ++v) {
            float4 send = b0 ? acc[0][v] : acc[0][v + 2];
            float4 keep = b0 ? acc[0][v + 2] : acc[0][v];
            float4 r = shfl_xor4(send, 8);
            acc[0][v] = make_float4(keep.x + r.x, keep.y + r.y,
                                    keep.z + r.z, keep.w + r.w);
        }
    }

    // ---- epilogue: lane owns row m8 + 8*(q8>>1), d in [8*(q8&1), +8) ----
    // out += partial * inv (linear in agg -> split-K/wave merge via atomics exact)
    {
        const int R = r0 + m8 + 8 * (q8 >> 1);
        const int d0 = 8 * (q8 & 1);
        const float* ivp = inv + (size_t)R * DIM + d0;
        float* op = out + (size_t)R * DIM + d0;
        float4 iv0 = *reinterpret_cast<const float4*>(ivp);
        float4 iv1 = *reinterpret_cast<const float4*>(ivp + 4);
        atomicAdd(op + 0, acc[0][0].x * iv0.x);
        atomicAdd(op + 1, acc[0][0].y * iv0.y);
        atomicAdd(op + 2, acc[0][0].z * iv0.z);
        atomicAdd(op + 3, acc[0][0].w * iv0.w);
        atomicAdd(op + 4, acc[0][1].x * iv1.x);
        atomicAdd(op + 5, acc[0][1].y * iv1.y);
        atomicAdd(op + 6, acc[0][1].z * iv1.z);
        atomicAdd(op + 7, acc[0][1].w * iv1.w);
    }
}

extern "C" void kernel_launch(void* const* d_in, const int* in_sizes, int n_in,
                              void* d_out, int out_size, void* d_ws, size_t ws_size,
                              hipStream_t stream) {
    const float* A = (const float*)d_in[0];
    const float* x = (const float*)d_in[1];
    float* out = (float*)d_out;
    float* xhp = (float*)d_ws;                      // 1 MiB
    float* inv = (float*)d_ws + (size_t)NN * DIM;   // 1 MiB

    prep_kernel<<<(NN * DIM / 4) / 256, 256, 0, stream>>>(x, out, xhp, inv);
    agg_kernel<<<NRB * KSPLIT, TPB, 0, stream>>>(A, xhp, inv, out);
}